// Round 8
// baseline (309.425 us; speedup 1.0000x reference)
//
#include <hip/hip_runtime.h>
#include <hip/hip_bf16.h>

// b=2048, m=8192, d=1024, 2d=2048, out=1000. fp32 in/out, bf16 MFMA GEMMs.
// Z (cosine scores) in fp16. sparsemax+gather fused; gather reads bf16 rows
// (fp8 gather tried r8: absmax 1.46e-2 > 1.18e-2 threshold — reverted).
// r11: Z row in registers (LDS 23->6.5KB, occ 52->63%), 60.5us. CLEAN.
// r12/r13: 512-thr block REGRESSED (rows/CU halved). r14/r15: pipeline ARRAY
// -> scratch spill (WRITE 432/114MB). r16: predicated at-use weights cost
// VALU+occ (66us). Lessons: named scalars only; keep skeleton lean.
// r17: fdot2 Pass A + single-threshold packed Pass B + fma_mix gather:
// VALUBusy 44->35%, 58us. Dur barely moved though -> NOT VALU-bound.
// r18: latency/in-flight attack. All 2048 blocks co-resident; gather serves
// ~470MB from L2/L3; outstanding bytes ~0.5MB vs ~2MB BDP -> 4x under-
// subscribed. Gather unroll x4 -> x8 with TRANSIENT named scalars v0..v7
// (32 VGPR transient, fits 64 cap; r11-shape so no spill). Doubles in-flight
// loads. If null with clean counters -> L3 BW is the wall, next is bytes.
// GEMM: BMxBN block, WMxWN wave tiles, BK=64, XOR-swizzled LDS staging
// (0 bank conflicts, measured r5), shfl-packed epilogue stores.

#define TPB 256
#define CAP 1024   // compact-list capacity; fallback path if exceeded

typedef __bf16 bf16x8 __attribute__((ext_vector_type(8)));
typedef float  f32x4  __attribute__((ext_vector_type(4)));
typedef _Float16 half2_t __attribute__((ext_vector_type(2)));

typedef const __attribute__((address_space(1))) void* gas_ptr;
typedef __attribute__((address_space(3))) void*       las_ptr;

#if defined(__has_builtin)
# if __has_builtin(__builtin_amdgcn_fdot2) && __has_builtin(__builtin_elementwise_max)
#  define HAVE_PK16 1
# endif
#endif
#ifndef HAVE_PK16
# define HAVE_PK16 0
#endif

__device__ __forceinline__ unsigned short f2bf(float f) {
    __hip_bfloat16 h = __float2bfloat16(f);
    union { __hip_bfloat16 h; unsigned short s; } u; u.h = h; return u.s;
}
__device__ __forceinline__ float bf2f(unsigned short s) {
    union { unsigned int b; float f; } u; u.b = (unsigned int)s << 16; return u.f;
}
__device__ __forceinline__ unsigned short f2h(float f) {
    union { _Float16 h; unsigned short s; } u; u.h = (_Float16)f; return u.s;
}
__device__ __forceinline__ float h2f(unsigned short s) {
    union { unsigned short s; _Float16 h; } u; u.s = s; return (float)u.h;
}

__device__ __forceinline__ float block_reduce_sum(float v, float* sred) {
    #pragma unroll
    for (int off = 32; off > 0; off >>= 1) v += __shfl_down(v, off, 64);
    int lane = threadIdx.x & 63, wid = threadIdx.x >> 6;
    if (lane == 0) sred[wid] = v;
    __syncthreads();
    if (threadIdx.x == 0) sred[0] = sred[0] + sred[1] + sred[2] + sred[3];
    __syncthreads();
    float r = sred[0];
    __syncthreads();
    return r;
}

__device__ __forceinline__ void block_reduce_sum2(float& a, float& b, float* sred) {
    #pragma unroll
    for (int off = 32; off > 0; off >>= 1) {
        a += __shfl_down(a, off, 64);
        b += __shfl_down(b, off, 64);
    }
    int lane = threadIdx.x & 63, wid = threadIdx.x >> 6;
    if (lane == 0) { sred[wid] = a; sred[4 + wid] = b; }
    __syncthreads();
    if (threadIdx.x == 0) {
        sred[0] = sred[0] + sred[1] + sred[2] + sred[3];
        sred[4] = sred[4] + sred[5] + sred[6] + sred[7];
    }
    __syncthreads();
    a = sred[0]; b = sred[4];
    __syncthreads();
}

// Merged: rows [0,nrow0) normalize X0->Y0 (bf16); rest X1->Y1 (bf16) + norm.
__global__ __launch_bounds__(TPB) void normalize_rows_bf16(const float* __restrict__ X0,
                                                           unsigned short* __restrict__ Y0,
                                                           const float* __restrict__ X1,
                                                           unsigned short* __restrict__ Y1,
                                                           float* __restrict__ norms1,
                                                           int nrow0, int cols) {
    __shared__ float sred[4];
    int r = blockIdx.x, tid = threadIdx.x;
    const float* X; unsigned short* Y; float* nn; int row;
    if (r < nrow0) { X = X0; Y = Y0; nn = nullptr; row = r; }
    else           { X = X1; Y = Y1; nn = norms1; row = r - nrow0; }
    const float4* x4 = (const float4*)(X + (size_t)row * cols);
    ushort4* y4 = (ushort4*)(Y + (size_t)row * cols);
    int n4 = cols >> 2;
    float ss = 0.f;
    for (int i = tid; i < n4; i += TPB) {
        float4 v = x4[i];
        ss += v.x * v.x + v.y * v.y + v.z * v.z + v.w * v.w;
    }
    float tot = block_reduce_sum(ss, sred);
    float nrm = sqrtf(tot + 1e-6f);
    float inv = 1.0f / nrm;
    if (nn && tid == 0) nn[row] = nrm;
    for (int i = tid; i < n4; i += TPB) {
        float4 v = x4[i];
        ushort4 o;
        o.x = f2bf(v.x * inv); o.y = f2bf(v.y * inv);
        o.z = f2bf(v.z * inv); o.w = f2bf(v.w * inv);
        y4[i] = o;
    }
}

// Two transposes (W1 and W2) in one launch. in fp32 [R][C] -> out bf16 [Cpad][R].
__device__ __forceinline__ void tc_body(const float* in, unsigned short* out,
                                        int R, int C, int Cpad, int bx, int by) {
    __shared__ float t[32][33];
    int x = threadIdx.x & 31, y = threadIdx.x >> 5;
    int r0 = by * 32, c0 = bx * 32;
    #pragma unroll
    for (int yy = y; yy < 32; yy += 8) {
        int c = c0 + x;
        t[yy][x] = (c < C) ? in[(size_t)(r0 + yy) * C + c] : 0.f;
    }
    __syncthreads();
    #pragma unroll
    for (int yy = y; yy < 32; yy += 8) {
        int c = c0 + yy;
        if (c < Cpad)
            out[(size_t)c * R + r0 + x] = f2bf(t[x][yy]);
    }
}

__global__ __launch_bounds__(TPB) void transpose_cast2(const float* __restrict__ in1,
                                                       unsigned short* __restrict__ out1,
                                                       int R1, int C1, int Cp1,
                                                       const float* __restrict__ in2,
                                                       unsigned short* __restrict__ out2,
                                                       int R2, int C2, int Cp2,
                                                       int nblk1) {
    int bid = blockIdx.x;
    if (bid < nblk1) {
        int nx = Cp1 / 32;
        tc_body(in1, out1, R1, C1, Cp1, bid % nx, bid / nx);
    } else {
        bid -= nblk1;
        int nx = Cp2 / 32;
        tc_body(in2, out2, R2, C2, Cp2, bid % nx, bid / nx);
    }
}

// acc += w * row (bf16x8). (float)__bf16 + fmaf lets gfx950 pattern-match
// v_fma_mix_f32_bf16 (no explicit unpack); falls back to shift+fma harmlessly.
__device__ __forceinline__ void acc8b(float* acc, float w, bf16x8 v) {
    #pragma unroll
    for (int k = 0; k < 8; ++k)
        acc[k] = fmaf(w, (float)v[k], acc[k]);
}

// Fused sparsemax (Michelot, exact, moment head-start) + bf16 gather:
// mv[row] = sum_i sparsemax(z)_i * mem_i = sum_i (z_i - tau) * ynorm_i * yhat_i.
// Z row in registers for Pass A-C only: NR=4 uint4/thread (m = TPB*8*NR).
__global__ __launch_bounds__(TPB, 8) void sparsemax_gather(const unsigned short* __restrict__ Zh,
                                                           const float* __restrict__ ynorm,
                                                           const unsigned short* __restrict__ yn,
                                                           unsigned short* __restrict__ mv,
                                                           int m, int d) {
    __shared__ float sred[16];
    __shared__ unsigned short cidx[CAP];
    __shared__ float cval[CAP];        // z during Michelot; weights after fold;
                                       // transposed combine scratch at the end
    __shared__ unsigned int lcnt;
    constexpr int NR = 4;              // m / (TPB*8)
    int row = blockIdx.x, tid = threadIdx.x;
    const uint4* zr8 = (const uint4*)(Zh + (size_t)row * m);

    float tau1;
    {
        // zreg scope ends at Pass C so its 16 VGPRs are reusable by the
        // gather (fallback re-reads global Z; r14 spill lesson).
        uint4 zreg[NR];
        float s = 0.f, q = 0.f;
#if HAVE_PK16
        const half2_t ones2 = {(_Float16)1.f, (_Float16)1.f};
#endif
        // Pass A: load row + sum + sumsq (fdot2: 1 op/elem).
        #pragma unroll
        for (int j = 0; j < NR; ++j) {
            uint4 v = zr8[tid + j * TPB];
            zreg[j] = v;
            unsigned int ww[4] = {v.x, v.y, v.z, v.w};
            #pragma unroll
            for (int k = 0; k < 4; ++k) {
#if HAVE_PK16
                union { unsigned int u; half2_t h; } pu; pu.u = ww[k];
                s = __builtin_amdgcn_fdot2(pu.h, ones2, s, false);
                q = __builtin_amdgcn_fdot2(pu.h, pu.h, q, false);
#else
                float a = h2f((unsigned short)(ww[k] & 0xffffu));
                float bq = h2f((unsigned short)(ww[k] >> 16));
                s += a + bq; q += a * a + bq * bq;
#endif
            }
        }
        if (tid == 0) lcnt = 0;
        block_reduce_sum2(s, q, sred);
        float fm   = (float)m;
        float mean = s / fm;
        float sig  = sqrtf(fmaxf(q / fm - mean * mean, 0.f));
        float tau_s = (s - 1.f) / fm;
        // quantize tau_g to f16 so packed stats are exactly "stats at tgf"
        _Float16 tgh = (_Float16)(mean + 2.f * sig);
        float tgf = (float)tgh;

        // Pass B: excess-sum & count at tau_g ONLY (common case).
        float Sg = 0.f, cg = 0.f;
#if HAVE_PK16
        const half2_t tg2 = {tgh, tgh};
        const half2_t zero2 = {(_Float16)0.f, (_Float16)0.f};
#endif
        #pragma unroll
        for (int j = 0; j < NR; ++j) {
            unsigned int ww[4] = {zreg[j].x, zreg[j].y, zreg[j].z, zreg[j].w};
            #pragma unroll
            for (int k = 0; k < 4; ++k) {
#if HAVE_PK16
                union { unsigned int u; half2_t h; } pu; pu.u = ww[k];
                half2_t e = __builtin_elementwise_max(pu.h - tg2, zero2);
                Sg = __builtin_amdgcn_fdot2(e, ones2, Sg, false);
                if (e[0] > (_Float16)0.f) cg += 1.f;
                if (e[1] > (_Float16)0.f) cg += 1.f;
#else
                float a = h2f((unsigned short)(ww[k] & 0xffffu));
                float bq = h2f((unsigned short)(ww[k] >> 16));
                if (a > tgf)  { Sg += a - tgf;  cg += 1.f; }
                if (bq > tgf) { Sg += bq - tgf; cg += 1.f; }
#endif
            }
        }
        block_reduce_sum2(Sg, cg, sred);

        if (Sg >= 1.f) {
            tau1 = tgf + (Sg - 1.f) / cg;          // Michelot step from tgf
            if (tau1 < tgf) tau1 = tgf;
        } else {
            // rare: weak tail. Exact stats at the safe lower bound tau_s.
            float Ss = 0.f, cs = 0.f;
            #pragma unroll
            for (int j = 0; j < NR; ++j) {
                unsigned int ww[4] = {zreg[j].x, zreg[j].y, zreg[j].z, zreg[j].w};
                #pragma unroll
                for (int k = 0; k < 4; ++k) {
                    float a = h2f((unsigned short)(ww[k] & 0xffffu));
                    float bq = h2f((unsigned short)(ww[k] >> 16));
                    if (a > tau_s)  { Ss += a - tau_s;  cs += 1.f; }
                    if (bq > tau_s) { Ss += bq - tau_s; cs += 1.f; }
                }
            }
            block_reduce_sum2(Ss, cs, sred);
            tau1 = tau_s + (Ss - 1.f) / cs;
            if (tau1 < tau_s) tau1 = tau_s;
        }

        // Pass C: compact actives at tau1 (exact f32 compares).
        #pragma unroll
        for (int j = 0; j < NR; ++j) {
            int base = (tid + j * TPB) * 8;
            unsigned int ww[4] = {zreg[j].x, zreg[j].y, zreg[j].z, zreg[j].w};
            #pragma unroll
            for (int k = 0; k < 4; ++k) {
                float a = h2f((unsigned short)(ww[k] & 0xffffu));
                float bq = h2f((unsigned short)(ww[k] >> 16));
                if (a > tau1) {
                    unsigned int slot = atomicAdd(&lcnt, 1u);
                    if (slot < CAP) { cidx[slot] = (unsigned short)(base + 2 * k); cval[slot] = a; }
                }
                if (bq > tau1) {
                    unsigned int slot = atomicAdd(&lcnt, 1u);
                    if (slot < CAP) { cidx[slot] = (unsigned short)(base + 2 * k + 1); cval[slot] = bq; }
                }
            }
        }
    }
    __syncthreads();

    int fast = (lcnt <= CAP && lcnt > 0);
    float tau = tau1;
    int n = (int)lcnt;
    if (fast) {
        // list-Michelot on wave 0 only (n <= 1024): shuffle reductions, no
        // block-wide barriers inside the iteration loop.
        if ((tid >> 6) == 0) {
            int lane = tid & 63;
            float tau_l = tau1, prev = -1.f;
            for (int it = 0; it < 64; ++it) {
                float S = 0.f, c = 0.f;
                for (int jj = lane; jj < n; jj += 64) {
                    float z = cval[jj];
                    if (z > tau_l) { S += z; c += 1.f; }
                }
                #pragma unroll
                for (int off = 32; off > 0; off >>= 1) {
                    S += __shfl_down(S, off, 64);
                    c += __shfl_down(c, off, 64);
                }
                S = __shfl(S, 0, 64);
                c = __shfl(c, 0, 64);
                if (c < 0.5f || c == prev) break;
                tau_l = (S - 1.f) / c; prev = c;
            }
            if (lane == 0) sred[0] = tau_l;
        }
        __syncthreads();
        tau = sred[0];
        // fold norm into weights (<=0 entries become 0; gather is branchless)
        for (int jj = tid; jj < n; jj += TPB) {
            float w = cval[jj] - tau;
            cval[jj] = (w > 0.f) ? w * ynorm[cidx[jj]] : 0.f;
        }
        __syncthreads();
    } else {
        // rare: n > CAP. Michelot re-reading Z from global (L2/L3-resident).
        float prev = -1.f;
        for (int it = 0; it < 64; ++it) {
            float S = 0.f, c = 0.f;
            for (int i8 = tid; i8 < (m >> 3); i8 += TPB) {
                uint4 v = zr8[i8];
                unsigned int ww[4] = {v.x, v.y, v.z, v.w};
                #pragma unroll
                for (int k = 0; k < 4; ++k) {
                    float a = h2f((unsigned short)(ww[k] & 0xffffu));
                    float bq = h2f((unsigned short)(ww[k] >> 16));
                    if (a > tau) { S += a; c += 1.f; }
                    if (bq > tau) { S += bq; c += 1.f; }
                }
            }
            block_reduce_sum2(S, c, sred);
            if (c < 0.5f || c == prev) break;
            tau = (S - 1.f) / c; prev = c;
        }
    }

    // Gather (bf16 rows, 2 KB each): two 128-thread groups, 8 cols/thread.
    // x8 unroll with TRANSIENT named scalars: 8 loads in flight per thread
    // (r18 — doubles offered load; BDP was 4x under-subscribed at x4).
    int g = tid >> 7;
    int c0 = (tid & 127) * 8;    // d = 1024 = 128*8
    float acc[8] = {};
    if (fast) {
        int j = g;
        for (; j + 14 < n; j += 16) {
            int i0 = cidx[j],      i1 = cidx[j + 2];
            int i2 = cidx[j + 4],  i3 = cidx[j + 6];
            int i4 = cidx[j + 8],  i5 = cidx[j + 10];
            int i6 = cidx[j + 12], i7 = cidx[j + 14];
            float w0 = cval[j],      w1 = cval[j + 2];
            float w2 = cval[j + 4],  w3 = cval[j + 6];
            float w4 = cval[j + 8],  w5 = cval[j + 10];
            float w6 = cval[j + 12], w7 = cval[j + 14];
            bf16x8 v0 = *(const bf16x8*)&yn[(size_t)i0 * d + c0];
            bf16x8 v1 = *(const bf16x8*)&yn[(size_t)i1 * d + c0];
            bf16x8 v2 = *(const bf16x8*)&yn[(size_t)i2 * d + c0];
            bf16x8 v3 = *(const bf16x8*)&yn[(size_t)i3 * d + c0];
            bf16x8 v4 = *(const bf16x8*)&yn[(size_t)i4 * d + c0];
            bf16x8 v5 = *(const bf16x8*)&yn[(size_t)i5 * d + c0];
            bf16x8 v6 = *(const bf16x8*)&yn[(size_t)i6 * d + c0];
            bf16x8 v7 = *(const bf16x8*)&yn[(size_t)i7 * d + c0];
            acc8b(acc, w0, v0); acc8b(acc, w1, v1);
            acc8b(acc, w2, v2); acc8b(acc, w3, v3);
            acc8b(acc, w4, v4); acc8b(acc, w5, v5);
            acc8b(acc, w6, v6); acc8b(acc, w7, v7);
        }
        for (; j < n; j += 2) {
            float w = cval[j];
            int idx = (int)cidx[j];
            bf16x8 v = *(const bf16x8*)&yn[(size_t)idx * d + c0];
            acc8b(acc, w, v);
        }
    } else {
        // rare path: weights recomputed from global Z (L2/L3-resident)
        const unsigned short* zrow = Zh + (size_t)row * m;
        for (int i = g; i < m; i += 2) {
            float w = h2f(zrow[i]) - tau;
            if (w <= 0.f) continue;
            w *= ynorm[i];
            bf16x8 v = *(const bf16x8*)&yn[(size_t)i * d + c0];
            acc8b(acc, w, v);
        }
    }
    __syncthreads();
    // combine: transposed layout (lanes write consecutive 4B -> no conflicts)
    int tcol = tid & 127;
    if (g == 1) {
        #pragma unroll
        for (int k = 0; k < 8; ++k) cval[k * 128 + tcol] = acc[k];
    }
    __syncthreads();
    if (g == 0) {
        #pragma unroll
        for (int k = 0; k < 8; ++k) acc[k] += cval[k * 128 + tcol];
        unsigned int w0 = f2bf(acc[0]) | ((unsigned int)f2bf(acc[1]) << 16);
        unsigned int w1 = f2bf(acc[2]) | ((unsigned int)f2bf(acc[3]) << 16);
        unsigned int w2 = f2bf(acc[4]) | ((unsigned int)f2bf(acc[5]) << 16);
        unsigned int w3 = f2bf(acc[6]) | ((unsigned int)f2bf(acc[7]) << 16);
        uint4 st = {w0, w1, w2, w3};
        *(uint4*)&mv[(size_t)row * d + c0] = st;
    }
}

// C[M][ldc] = A[M][lda] * B^T (+bias)(+relu). B is [Npad][K] bf16 row-major.
// BM x BN block tile, WM x WN wave tiles, BK=64, XOR-swizzled staging
// (swizzle on global addr; LDS dest lane-contiguous). Launch (BM/WM)*(BN/WN)*64 thr.
// OUTMODE: 0=f32, 1=bf16, 2=f16.
template <int BM, int BN, int WM, int WN, int OUTMODE, int RELU, int HASBIAS>
__global__ __launch_bounds__((BM / WM) * (BN / WN) * 64)
void gemm_bt(const unsigned short* __restrict__ A,
             const unsigned short* __restrict__ B,
             const float* __restrict__ bias,
             void* __restrict__ C,
             int M, int K, int lda, int NOUT, int ldc) {
    constexpr int NW   = (BM / WM) * (BN / WN);
    constexpr int TPBL = NW * 64;
    constexpr int ITM  = WM / 16;
    constexpr int ITN  = WN / 16;
    __shared__ unsigned short lA[BM * 64];
    __shared__ unsigned short lB[BN * 64];
    int tid = threadIdx.x;
    int lane = tid & 63, wv = tid >> 6;
    int wm = (wv % (BM / WM)) * WM;
    int wn = (wv / (BM / WM)) * WN;
    int lr = lane & 15, kq = lane >> 4;

    int rowBase = blockIdx.y * BM;
    int colBase = blockIdx.x * BN;

    f32x4 acc[ITM][ITN] = {};

    for (int k0 = 0; k0 < K; k0 += 64) {
        constexpr int AI = BM * 8 / TPBL;
        #pragma unroll
        for (int l = 0; l < AI; ++l) {
            int li = l * TPBL + tid;
            int row = li >> 3, s0 = li & 7;
            int seg = s0 ^ (row & 7);
            const char* gp = (const char*)(A + (size_t)(rowBase + row) * lda + k0) + seg * 16;
            __builtin_amdgcn_global_load_lds((gas_ptr)gp, (las_ptr)((char*)lA + li * 16), 16, 0, 0);
        }
        constexpr int BI = BN * 8 / TPBL;
        #pragma unroll
        for (int l = 0; l < BI; ++l) {
            int li = l * TPBL + tid;
            int row = li >> 3, s0 = li & 7;
            int seg = s0 ^ (row & 7);
            const char* gp = (const char*)(B + (size_t)(colBase + row) * K + k0) + seg * 16;
            __builtin_amdgcn_global_load_lds((gas_ptr)gp, (las_ptr)((char*)lB + li * 16), 16, 0, 0);
        }
        __syncthreads();

        #pragma unroll
        for (int h = 0; h < 2; ++h) {
            bf16x8 av[ITM], bv[ITN];
            #pragma unroll
            for (int i = 0; i < ITM; ++i) {
                int row = wm + i * 16 + lr;
                av[i] = *(const bf16x8*)((const char*)lA + row * 128
                                         + ((((h << 2) | kq) ^ (row & 7)) * 16));
            }
            #pragma unroll
            for (int j = 0; j < ITN; ++j) {
                int row = wn + j * 16 + lr;
                bv[j] = *(const bf16x8*)((const char*)lB + row * 128
                                         + ((((h << 2) | kq) ^ (row & 7)) * 16));
            }
            #pragma unroll
            for (int i = 0; i < ITM; ++i)
                #pragma unroll
                for (int j = 0; j < ITN; ++j)
                    acc[i][j] = __builtin_amdgcn_mfma_f32_16x16x32_bf16(av[i], bv[j], acc[i][j], 0, 0, 0);
        }
        __syncthreads();
    }

    // Epilogue. C/D layout: col = lane&15, row = kq*4+r. Packed stores.
    float* Cf = (float*)C;
    unsigned short* Cb = (unsigned short*)C;
    bool fullN = (colBase + BN) <= NOUT;
    #pragma unroll
    for (int j = 0; j < ITN; ++j) {
        int col = colBase + wn + j * 16 + lr;
        float bv_ = (HASBIAS && col < NOUT) ? bias[col] : 0.f;
        #pragma unroll
        for (int i = 0; i < ITM; ++i) {
            #pragma unroll
            for (int r = 0; r < 4; ++r) {
                int row = rowBase + wm + i * 16 + kq * 4 + r;
                float v = acc[i][j][r] + bv_;
                if (RELU) v = fmaxf(v, 0.f);
                if (OUTMODE == 0) {
                    float p = __shfl_xor(v, 1, 64);
                    if (fullN) {
                        if (!(lr & 1)) { float2 st = {v, p}; *(float2*)&Cf[(size_t)row * ldc + col] = st; }
                    } else if (col < NOUT) {
                        Cf[(size_t)row * ldc + col] = v;
                    }
                } else {
                    unsigned int hh = (OUTMODE == 1) ? (unsigned int)f2bf(v) : (unsigned int)f2h(v);
                    unsigned int p1 = (unsigned int)__shfl_xor((int)hh, 1, 64);
                    unsigned int u = (hh & 0xffffu) | (p1 << 16);
                    unsigned int p2 = (unsigned int)__shfl_xor((int)u, 2, 64);
                    if (fullN) {
                        if (!(lr & 3)) { uint2 st = {u, p2}; *(uint2*)&Cb[(size_t)row * ldc + col] = st; }
                    } else if (col < NOUT) {
                        Cb[(size_t)row * ldc + col] = (unsigned short)hh;
                    }
                }
            }
        }
    }
}

extern "C" void kernel_launch(void* const* d_in, const int* in_sizes, int n_in,
                              void* d_out, int out_size, void* d_ws, size_t ws_size,
                              hipStream_t stream) {
    const float* enc = (const float*)d_in[0];   // [b, d]
    const float* mem = (const float*)d_in[1];   // [m, d]
    const float* W1  = (const float*)d_in[2];   // [d, 2d]
    const float* b1  = (const float*)d_in[3];   // [2d]
    const float* W2  = (const float*)d_in[4];   // [2d, out]
    const float* b2  = (const float*)d_in[5];   // [out]

    const int d    = in_sizes[3] / 2;           // 1024
    const int b    = in_sizes[0] / d;           // 2048
    const int m    = in_sizes[1] / d;           // 8192
    const int d2   = in_sizes[3];               // 2048
    const int outN = in_sizes[5];               // 1000
    const int outPad = 1024;

    unsigned short* xn    = (unsigned short*)d_ws;                    // [b][d] bf16
    unsigned short* yn    = xn  + (size_t)b * d;                      // [m][d] bf16
    float*          ynorm = (float*)(yn + (size_t)m * d);             // [m] fp32
    unsigned short* W1T   = (unsigned short*)(ynorm + m);             // [2d][d] bf16
    unsigned short* W2T   = W1T + (size_t)d2 * d;                     // [outPad][2d] bf16
    unsigned short* Zh    = W2T + (size_t)outPad * d2;                // [b][m] fp16
    unsigned short* mv    = Zh + (size_t)b * m;                       // [b][d] bf16
    unsigned short* h     = mv + (size_t)b * d;                       // [b][2d] bf16

    // normalize enc->xn and mem->yn (+norms) in one launch
    normalize_rows_bf16<<<b + m, TPB, 0, stream>>>(enc, xn, mem, yn, ynorm, b, d);

    // W1 [d][2d]->W1T [2d][d]  and  W2 [2d][outN]->W2T [outPad][2d] in one launch
    int nblk1 = (d2 / 32) * (d / 32);
    int nblk2 = (outPad / 32) * (d2 / 32);
    transpose_cast2<<<nblk1 + nblk2, TPB, 0, stream>>>(W1, W1T, d, d2, d2,
                                                       W2, W2T, d2, outN, outPad, nblk1);

    // Z = xn * yn^T  [b][m] fp16.  BM=256 x BN=128, 8 waves (512 thr).
    gemm_bt<256, 128, 64, 64, 2, 0, 0><<<dim3(m / 128, b / 256), 512, 0, stream>>>(
        xn, yn, nullptr, Zh, b, d, d, m, m);

    // fused sparsemax + bf16 gather -> mv
    sparsemax_gather<<<b, TPB, 0, stream>>>(Zh, ynorm, yn, mv, m, d);

    // h = relu(mv * W1 + b1)  [b][2d] bf16.  4 waves (256 thr).
    gemm_bt<128, 128, 64, 64, 1, 1, 1><<<dim3(d2 / 128, b / 128), 256, 0, stream>>>(
        mv, W1T, b1, h, b, d, d, d2, d2);

    // out = h * W2 + b2  [b][outN] fp32.  32x64 wave tiles -> 4 waves (256 thr).
    gemm_bt<128, 64, 32, 64, 0, 0, 1><<<dim3(outPad / 64, b / 128), 256, 0, stream>>>(
        h, W2T, b2, d_out, b, d2, d2, outN, outN);
}

// Round 9
// 263.186 us; speedup vs baseline: 1.1757x; 1.1757x over previous
//
#include <hip/hip_runtime.h>
#include <hip/hip_bf16.h>

// b=2048, m=8192, d=1024, 2d=2048, out=1000. fp32 in/out, bf16 MFMA GEMMs.
// Z (cosine scores) in fp16. sparsemax+gather fused; gather reads bf16 rows
// (fp8 gather tried r8: absmax 1.46e-2 > 1.18e-2 threshold — reverted).
// r11: Z row in registers (LDS 23->6.5KB), 60.5us. CLEAN.
// r12/r13: 512-thr REGRESSED (rows/CU halved). r14/r15: pipeline ARRAY ->
// scratch spill. r16: predicated at-use weights cost VALU+occ (66us).
// r17: fdot2 Pass A + single-threshold packed Pass B + fma_mix gather:
// VALUBusy 44->35%, 58us BEST. Dur barely moved -> NOT VALU-bound.
// r18: gather x8 unroll SPILLED (WRITE 4->145MB, 108us): peak window
// 8x4(v)+8(acc)+8(w)+8(idx)+addr ~75 VGPR > 64 cap. Tripwire fired.
// r19: back off to x6 per decision rule: window ~54 VGPR fits under 64.
// In-flight loads/thread 4->6 (offered load x1.5 vs the ~4x BDP
// under-subscription measured r18). All else = r17.
// GEMM: BMxBN block, WMxWN wave tiles, BK=64, XOR-swizzled LDS staging
// (0 bank conflicts, measured r5), shfl-packed epilogue stores.

#define TPB 256
#define CAP 1024   // compact-list capacity; fallback path if exceeded

typedef __bf16 bf16x8 __attribute__((ext_vector_type(8)));
typedef float  f32x4  __attribute__((ext_vector_type(4)));
typedef _Float16 half2_t __attribute__((ext_vector_type(2)));

typedef const __attribute__((address_space(1))) void* gas_ptr;
typedef __attribute__((address_space(3))) void*       las_ptr;

#if defined(__has_builtin)
# if __has_builtin(__builtin_amdgcn_fdot2) && __has_builtin(__builtin_elementwise_max)
#  define HAVE_PK16 1
# endif
#endif
#ifndef HAVE_PK16
# define HAVE_PK16 0
#endif

__device__ __forceinline__ unsigned short f2bf(float f) {
    __hip_bfloat16 h = __float2bfloat16(f);
    union { __hip_bfloat16 h; unsigned short s; } u; u.h = h; return u.s;
}
__device__ __forceinline__ float bf2f(unsigned short s) {
    union { unsigned int b; float f; } u; u.b = (unsigned int)s << 16; return u.f;
}
__device__ __forceinline__ unsigned short f2h(float f) {
    union { _Float16 h; unsigned short s; } u; u.h = (_Float16)f; return u.s;
}
__device__ __forceinline__ float h2f(unsigned short s) {
    union { unsigned short s; _Float16 h; } u; u.s = s; return (float)u.h;
}

__device__ __forceinline__ float block_reduce_sum(float v, float* sred) {
    #pragma unroll
    for (int off = 32; off > 0; off >>= 1) v += __shfl_down(v, off, 64);
    int lane = threadIdx.x & 63, wid = threadIdx.x >> 6;
    if (lane == 0) sred[wid] = v;
    __syncthreads();
    if (threadIdx.x == 0) sred[0] = sred[0] + sred[1] + sred[2] + sred[3];
    __syncthreads();
    float r = sred[0];
    __syncthreads();
    return r;
}

__device__ __forceinline__ void block_reduce_sum2(float& a, float& b, float* sred) {
    #pragma unroll
    for (int off = 32; off > 0; off >>= 1) {
        a += __shfl_down(a, off, 64);
        b += __shfl_down(b, off, 64);
    }
    int lane = threadIdx.x & 63, wid = threadIdx.x >> 6;
    if (lane == 0) { sred[wid] = a; sred[4 + wid] = b; }
    __syncthreads();
    if (threadIdx.x == 0) {
        sred[0] = sred[0] + sred[1] + sred[2] + sred[3];
        sred[4] = sred[4] + sred[5] + sred[6] + sred[7];
    }
    __syncthreads();
    a = sred[0]; b = sred[4];
    __syncthreads();
}

// Merged: rows [0,nrow0) normalize X0->Y0 (bf16); rest X1->Y1 (bf16) + norm.
__global__ __launch_bounds__(TPB) void normalize_rows_bf16(const float* __restrict__ X0,
                                                           unsigned short* __restrict__ Y0,
                                                           const float* __restrict__ X1,
                                                           unsigned short* __restrict__ Y1,
                                                           float* __restrict__ norms1,
                                                           int nrow0, int cols) {
    __shared__ float sred[4];
    int r = blockIdx.x, tid = threadIdx.x;
    const float* X; unsigned short* Y; float* nn; int row;
    if (r < nrow0) { X = X0; Y = Y0; nn = nullptr; row = r; }
    else           { X = X1; Y = Y1; nn = norms1; row = r - nrow0; }
    const float4* x4 = (const float4*)(X + (size_t)row * cols);
    ushort4* y4 = (ushort4*)(Y + (size_t)row * cols);
    int n4 = cols >> 2;
    float ss = 0.f;
    for (int i = tid; i < n4; i += TPB) {
        float4 v = x4[i];
        ss += v.x * v.x + v.y * v.y + v.z * v.z + v.w * v.w;
    }
    float tot = block_reduce_sum(ss, sred);
    float nrm = sqrtf(tot + 1e-6f);
    float inv = 1.0f / nrm;
    if (nn && tid == 0) nn[row] = nrm;
    for (int i = tid; i < n4; i += TPB) {
        float4 v = x4[i];
        ushort4 o;
        o.x = f2bf(v.x * inv); o.y = f2bf(v.y * inv);
        o.z = f2bf(v.z * inv); o.w = f2bf(v.w * inv);
        y4[i] = o;
    }
}

// Two transposes (W1 and W2) in one launch. in fp32 [R][C] -> out bf16 [Cpad][R].
__device__ __forceinline__ void tc_body(const float* in, unsigned short* out,
                                        int R, int C, int Cpad, int bx, int by) {
    __shared__ float t[32][33];
    int x = threadIdx.x & 31, y = threadIdx.x >> 5;
    int r0 = by * 32, c0 = bx * 32;
    #pragma unroll
    for (int yy = y; yy < 32; yy += 8) {
        int c = c0 + x;
        t[yy][x] = (c < C) ? in[(size_t)(r0 + yy) * C + c] : 0.f;
    }
    __syncthreads();
    #pragma unroll
    for (int yy = y; yy < 32; yy += 8) {
        int c = c0 + yy;
        if (c < Cpad)
            out[(size_t)c * R + r0 + x] = f2bf(t[x][yy]);
    }
}

__global__ __launch_bounds__(TPB) void transpose_cast2(const float* __restrict__ in1,
                                                       unsigned short* __restrict__ out1,
                                                       int R1, int C1, int Cp1,
                                                       const float* __restrict__ in2,
                                                       unsigned short* __restrict__ out2,
                                                       int R2, int C2, int Cp2,
                                                       int nblk1) {
    int bid = blockIdx.x;
    if (bid < nblk1) {
        int nx = Cp1 / 32;
        tc_body(in1, out1, R1, C1, Cp1, bid % nx, bid / nx);
    } else {
        bid -= nblk1;
        int nx = Cp2 / 32;
        tc_body(in2, out2, R2, C2, Cp2, bid % nx, bid / nx);
    }
}

// acc += w * row (bf16x8). (float)__bf16 + fmaf lets gfx950 pattern-match
// v_fma_mix_f32_bf16 (no explicit unpack); falls back to shift+fma harmlessly.
__device__ __forceinline__ void acc8b(float* acc, float w, bf16x8 v) {
    #pragma unroll
    for (int k = 0; k < 8; ++k)
        acc[k] = fmaf(w, (float)v[k], acc[k]);
}

// Fused sparsemax (Michelot, exact, moment head-start) + bf16 gather:
// mv[row] = sum_i sparsemax(z)_i * mem_i = sum_i (z_i - tau) * ynorm_i * yhat_i.
// Z row in registers for Pass A-C only: NR=4 uint4/thread (m = TPB*8*NR).
__global__ __launch_bounds__(TPB, 8) void sparsemax_gather(const unsigned short* __restrict__ Zh,
                                                           const float* __restrict__ ynorm,
                                                           const unsigned short* __restrict__ yn,
                                                           unsigned short* __restrict__ mv,
                                                           int m, int d) {
    __shared__ float sred[16];
    __shared__ unsigned short cidx[CAP];
    __shared__ float cval[CAP];        // z during Michelot; weights after fold;
                                       // transposed combine scratch at the end
    __shared__ unsigned int lcnt;
    constexpr int NR = 4;              // m / (TPB*8)
    int row = blockIdx.x, tid = threadIdx.x;
    const uint4* zr8 = (const uint4*)(Zh + (size_t)row * m);

    float tau1;
    {
        // zreg scope ends at Pass C so its 16 VGPRs are reusable by the
        // gather (fallback re-reads global Z; r14 spill lesson).
        uint4 zreg[NR];
        float s = 0.f, q = 0.f;
#if HAVE_PK16
        const half2_t ones2 = {(_Float16)1.f, (_Float16)1.f};
#endif
        // Pass A: load row + sum + sumsq (fdot2: 1 op/elem).
        #pragma unroll
        for (int j = 0; j < NR; ++j) {
            uint4 v = zr8[tid + j * TPB];
            zreg[j] = v;
            unsigned int ww[4] = {v.x, v.y, v.z, v.w};
            #pragma unroll
            for (int k = 0; k < 4; ++k) {
#if HAVE_PK16
                union { unsigned int u; half2_t h; } pu; pu.u = ww[k];
                s = __builtin_amdgcn_fdot2(pu.h, ones2, s, false);
                q = __builtin_amdgcn_fdot2(pu.h, pu.h, q, false);
#else
                float a = h2f((unsigned short)(ww[k] & 0xffffu));
                float bq = h2f((unsigned short)(ww[k] >> 16));
                s += a + bq; q += a * a + bq * bq;
#endif
            }
        }
        if (tid == 0) lcnt = 0;
        block_reduce_sum2(s, q, sred);
        float fm   = (float)m;
        float mean = s / fm;
        float sig  = sqrtf(fmaxf(q / fm - mean * mean, 0.f));
        float tau_s = (s - 1.f) / fm;
        // quantize tau_g to f16 so packed stats are exactly "stats at tgf"
        _Float16 tgh = (_Float16)(mean + 2.f * sig);
        float tgf = (float)tgh;

        // Pass B: excess-sum & count at tau_g ONLY (common case).
        float Sg = 0.f, cg = 0.f;
#if HAVE_PK16
        const half2_t tg2 = {tgh, tgh};
        const half2_t zero2 = {(_Float16)0.f, (_Float16)0.f};
#endif
        #pragma unroll
        for (int j = 0; j < NR; ++j) {
            unsigned int ww[4] = {zreg[j].x, zreg[j].y, zreg[j].z, zreg[j].w};
            #pragma unroll
            for (int k = 0; k < 4; ++k) {
#if HAVE_PK16
                union { unsigned int u; half2_t h; } pu; pu.u = ww[k];
                half2_t e = __builtin_elementwise_max(pu.h - tg2, zero2);
                Sg = __builtin_amdgcn_fdot2(e, ones2, Sg, false);
                if (e[0] > (_Float16)0.f) cg += 1.f;
                if (e[1] > (_Float16)0.f) cg += 1.f;
#else
                float a = h2f((unsigned short)(ww[k] & 0xffffu));
                float bq = h2f((unsigned short)(ww[k] >> 16));
                if (a > tgf)  { Sg += a - tgf;  cg += 1.f; }
                if (bq > tgf) { Sg += bq - tgf; cg += 1.f; }
#endif
            }
        }
        block_reduce_sum2(Sg, cg, sred);

        if (Sg >= 1.f) {
            tau1 = tgf + (Sg - 1.f) / cg;          // Michelot step from tgf
            if (tau1 < tgf) tau1 = tgf;
        } else {
            // rare: weak tail. Exact stats at the safe lower bound tau_s.
            float Ss = 0.f, cs = 0.f;
            #pragma unroll
            for (int j = 0; j < NR; ++j) {
                unsigned int ww[4] = {zreg[j].x, zreg[j].y, zreg[j].z, zreg[j].w};
                #pragma unroll
                for (int k = 0; k < 4; ++k) {
                    float a = h2f((unsigned short)(ww[k] & 0xffffu));
                    float bq = h2f((unsigned short)(ww[k] >> 16));
                    if (a > tau_s)  { Ss += a - tau_s;  cs += 1.f; }
                    if (bq > tau_s) { Ss += bq - tau_s; cs += 1.f; }
                }
            }
            block_reduce_sum2(Ss, cs, sred);
            tau1 = tau_s + (Ss - 1.f) / cs;
            if (tau1 < tau_s) tau1 = tau_s;
        }

        // Pass C: compact actives at tau1 (exact f32 compares).
        #pragma unroll
        for (int j = 0; j < NR; ++j) {
            int base = (tid + j * TPB) * 8;
            unsigned int ww[4] = {zreg[j].x, zreg[j].y, zreg[j].z, zreg[j].w};
            #pragma unroll
            for (int k = 0; k < 4; ++k) {
                float a = h2f((unsigned short)(ww[k] & 0xffffu));
                float bq = h2f((unsigned short)(ww[k] >> 16));
                if (a > tau1) {
                    unsigned int slot = atomicAdd(&lcnt, 1u);
                    if (slot < CAP) { cidx[slot] = (unsigned short)(base + 2 * k); cval[slot] = a; }
                }
                if (bq > tau1) {
                    unsigned int slot = atomicAdd(&lcnt, 1u);
                    if (slot < CAP) { cidx[slot] = (unsigned short)(base + 2 * k + 1); cval[slot] = bq; }
                }
            }
        }
    }
    __syncthreads();

    int fast = (lcnt <= CAP && lcnt > 0);
    float tau = tau1;
    int n = (int)lcnt;
    if (fast) {
        // list-Michelot on wave 0 only (n <= 1024): shuffle reductions, no
        // block-wide barriers inside the iteration loop.
        if ((tid >> 6) == 0) {
            int lane = tid & 63;
            float tau_l = tau1, prev = -1.f;
            for (int it = 0; it < 64; ++it) {
                float S = 0.f, c = 0.f;
                for (int jj = lane; jj < n; jj += 64) {
                    float z = cval[jj];
                    if (z > tau_l) { S += z; c += 1.f; }
                }
                #pragma unroll
                for (int off = 32; off > 0; off >>= 1) {
                    S += __shfl_down(S, off, 64);
                    c += __shfl_down(c, off, 64);
                }
                S = __shfl(S, 0, 64);
                c = __shfl(c, 0, 64);
                if (c < 0.5f || c == prev) break;
                tau_l = (S - 1.f) / c; prev = c;
            }
            if (lane == 0) sred[0] = tau_l;
        }
        __syncthreads();
        tau = sred[0];
        // fold norm into weights (<=0 entries become 0; gather is branchless)
        for (int jj = tid; jj < n; jj += TPB) {
            float w = cval[jj] - tau;
            cval[jj] = (w > 0.f) ? w * ynorm[cidx[jj]] : 0.f;
        }
        __syncthreads();
    } else {
        // rare: n > CAP. Michelot re-reading Z from global (L2/L3-resident).
        float prev = -1.f;
        for (int it = 0; it < 64; ++it) {
            float S = 0.f, c = 0.f;
            for (int i8 = tid; i8 < (m >> 3); i8 += TPB) {
                uint4 v = zr8[i8];
                unsigned int ww[4] = {v.x, v.y, v.z, v.w};
                #pragma unroll
                for (int k = 0; k < 4; ++k) {
                    float a = h2f((unsigned short)(ww[k] & 0xffffu));
                    float bq = h2f((unsigned short)(ww[k] >> 16));
                    if (a > tau) { S += a; c += 1.f; }
                    if (bq > tau) { S += bq; c += 1.f; }
                }
            }
            block_reduce_sum2(S, c, sred);
            if (c < 0.5f || c == prev) break;
            tau = (S - 1.f) / c; prev = c;
        }
    }

    // Gather (bf16 rows, 2 KB each): two 128-thread groups, 8 cols/thread.
    // x6 unroll, TRANSIENT named scalars (6 loads in flight; x8 spilled r18).
    int g = tid >> 7;
    int c0 = (tid & 127) * 8;    // d = 1024 = 128*8
    float acc[8] = {};
    if (fast) {
        int j = g;
        for (; j + 10 < n; j += 12) {
            int i0 = cidx[j],      i1 = cidx[j + 2];
            int i2 = cidx[j + 4],  i3 = cidx[j + 6];
            int i4 = cidx[j + 8],  i5 = cidx[j + 10];
            float w0 = cval[j],      w1 = cval[j + 2];
            float w2 = cval[j + 4],  w3 = cval[j + 6];
            float w4 = cval[j + 8],  w5 = cval[j + 10];
            bf16x8 v0 = *(const bf16x8*)&yn[(size_t)i0 * d + c0];
            bf16x8 v1 = *(const bf16x8*)&yn[(size_t)i1 * d + c0];
            bf16x8 v2 = *(const bf16x8*)&yn[(size_t)i2 * d + c0];
            bf16x8 v3 = *(const bf16x8*)&yn[(size_t)i3 * d + c0];
            bf16x8 v4 = *(const bf16x8*)&yn[(size_t)i4 * d + c0];
            bf16x8 v5 = *(const bf16x8*)&yn[(size_t)i5 * d + c0];
            acc8b(acc, w0, v0); acc8b(acc, w1, v1);
            acc8b(acc, w2, v2); acc8b(acc, w3, v3);
            acc8b(acc, w4, v4); acc8b(acc, w5, v5);
        }
        for (; j < n; j += 2) {
            float w = cval[j];
            int idx = (int)cidx[j];
            bf16x8 v = *(const bf16x8*)&yn[(size_t)idx * d + c0];
            acc8b(acc, w, v);
        }
    } else {
        // rare path: weights recomputed from global Z (L2/L3-resident)
        const unsigned short* zrow = Zh + (size_t)row * m;
        for (int i = g; i < m; i += 2) {
            float w = h2f(zrow[i]) - tau;
            if (w <= 0.f) continue;
            w *= ynorm[i];
            bf16x8 v = *(const bf16x8*)&yn[(size_t)i * d + c0];
            acc8b(acc, w, v);
        }
    }
    __syncthreads();
    // combine: transposed layout (lanes write consecutive 4B -> no conflicts)
    int tcol = tid & 127;
    if (g == 1) {
        #pragma unroll
        for (int k = 0; k < 8; ++k) cval[k * 128 + tcol] = acc[k];
    }
    __syncthreads();
    if (g == 0) {
        #pragma unroll
        for (int k = 0; k < 8; ++k) acc[k] += cval[k * 128 + tcol];
        unsigned int w0 = f2bf(acc[0]) | ((unsigned int)f2bf(acc[1]) << 16);
        unsigned int w1 = f2bf(acc[2]) | ((unsigned int)f2bf(acc[3]) << 16);
        unsigned int w2 = f2bf(acc[4]) | ((unsigned int)f2bf(acc[5]) << 16);
        unsigned int w3 = f2bf(acc[6]) | ((unsigned int)f2bf(acc[7]) << 16);
        uint4 st = {w0, w1, w2, w3};
        *(uint4*)&mv[(size_t)row * d + c0] = st;
    }
}

// C[M][ldc] = A[M][lda] * B^T (+bias)(+relu). B is [Npad][K] bf16 row-major.
// BM x BN block tile, WM x WN wave tiles, BK=64, XOR-swizzled staging
// (swizzle on global addr; LDS dest lane-contiguous). Launch (BM/WM)*(BN/WN)*64 thr.
// OUTMODE: 0=f32, 1=bf16, 2=f16.
template <int BM, int BN, int WM, int WN, int OUTMODE, int RELU, int HASBIAS>
__global__ __launch_bounds__((BM / WM) * (BN / WN) * 64)
void gemm_bt(const unsigned short* __restrict__ A,
             const unsigned short* __restrict__ B,
             const float* __restrict__ bias,
             void* __restrict__ C,
             int M, int K, int lda, int NOUT, int ldc) {
    constexpr int NW   = (BM / WM) * (BN / WN);
    constexpr int TPBL = NW * 64;
    constexpr int ITM  = WM / 16;
    constexpr int ITN  = WN / 16;
    __shared__ unsigned short lA[BM * 64];
    __shared__ unsigned short lB[BN * 64];
    int tid = threadIdx.x;
    int lane = tid & 63, wv = tid >> 6;
    int wm = (wv % (BM / WM)) * WM;
    int wn = (wv / (BM / WM)) * WN;
    int lr = lane & 15, kq = lane >> 4;

    int rowBase = blockIdx.y * BM;
    int colBase = blockIdx.x * BN;

    f32x4 acc[ITM][ITN] = {};

    for (int k0 = 0; k0 < K; k0 += 64) {
        constexpr int AI = BM * 8 / TPBL;
        #pragma unroll
        for (int l = 0; l < AI; ++l) {
            int li = l * TPBL + tid;
            int row = li >> 3, s0 = li & 7;
            int seg = s0 ^ (row & 7);
            const char* gp = (const char*)(A + (size_t)(rowBase + row) * lda + k0) + seg * 16;
            __builtin_amdgcn_global_load_lds((gas_ptr)gp, (las_ptr)((char*)lA + li * 16), 16, 0, 0);
        }
        constexpr int BI = BN * 8 / TPBL;
        #pragma unroll
        for (int l = 0; l < BI; ++l) {
            int li = l * TPBL + tid;
            int row = li >> 3, s0 = li & 7;
            int seg = s0 ^ (row & 7);
            const char* gp = (const char*)(B + (size_t)(colBase + row) * K + k0) + seg * 16;
            __builtin_amdgcn_global_load_lds((gas_ptr)gp, (las_ptr)((char*)lB + li * 16), 16, 0, 0);
        }
        __syncthreads();

        #pragma unroll
        for (int h = 0; h < 2; ++h) {
            bf16x8 av[ITM], bv[ITN];
            #pragma unroll
            for (int i = 0; i < ITM; ++i) {
                int row = wm + i * 16 + lr;
                av[i] = *(const bf16x8*)((const char*)lA + row * 128
                                         + ((((h << 2) | kq) ^ (row & 7)) * 16));
            }
            #pragma unroll
            for (int j = 0; j < ITN; ++j) {
                int row = wn + j * 16 + lr;
                bv[j] = *(const bf16x8*)((const char*)lB + row * 128
                                         + ((((h << 2) | kq) ^ (row & 7)) * 16));
            }
            #pragma unroll
            for (int i = 0; i < ITM; ++i)
                #pragma unroll
                for (int j = 0; j < ITN; ++j)
                    acc[i][j] = __builtin_amdgcn_mfma_f32_16x16x32_bf16(av[i], bv[j], acc[i][j], 0, 0, 0);
        }
        __syncthreads();
    }

    // Epilogue. C/D layout: col = lane&15, row = kq*4+r. Packed stores.
    float* Cf = (float*)C;
    unsigned short* Cb = (unsigned short*)C;
    bool fullN = (colBase + BN) <= NOUT;
    #pragma unroll
    for (int j = 0; j < ITN; ++j) {
        int col = colBase + wn + j * 16 + lr;
        float bv_ = (HASBIAS && col < NOUT) ? bias[col] : 0.f;
        #pragma unroll
        for (int i = 0; i < ITM; ++i) {
            #pragma unroll
            for (int r = 0; r < 4; ++r) {
                int row = rowBase + wm + i * 16 + kq * 4 + r;
                float v = acc[i][j][r] + bv_;
                if (RELU) v = fmaxf(v, 0.f);
                if (OUTMODE == 0) {
                    float p = __shfl_xor(v, 1, 64);
                    if (fullN) {
                        if (!(lr & 1)) { float2 st = {v, p}; *(float2*)&Cf[(size_t)row * ldc + col] = st; }
                    } else if (col < NOUT) {
                        Cf[(size_t)row * ldc + col] = v;
                    }
                } else {
                    unsigned int hh = (OUTMODE == 1) ? (unsigned int)f2bf(v) : (unsigned int)f2h(v);
                    unsigned int p1 = (unsigned int)__shfl_xor((int)hh, 1, 64);
                    unsigned int u = (hh & 0xffffu) | (p1 << 16);
                    unsigned int p2 = (unsigned int)__shfl_xor((int)u, 2, 64);
                    if (fullN) {
                        if (!(lr & 3)) { uint2 st = {u, p2}; *(uint2*)&Cb[(size_t)row * ldc + col] = st; }
                    } else if (col < NOUT) {
                        Cb[(size_t)row * ldc + col] = (unsigned short)hh;
                    }
                }
            }
        }
    }
}

extern "C" void kernel_launch(void* const* d_in, const int* in_sizes, int n_in,
                              void* d_out, int out_size, void* d_ws, size_t ws_size,
                              hipStream_t stream) {
    const float* enc = (const float*)d_in[0];   // [b, d]
    const float* mem = (const float*)d_in[1];   // [m, d]
    const float* W1  = (const float*)d_in[2];   // [d, 2d]
    const float* b1  = (const float*)d_in[3];   // [2d]
    const float* W2  = (const float*)d_in[4];   // [2d, out]
    const float* b2  = (const float*)d_in[5];   // [out]

    const int d    = in_sizes[3] / 2;           // 1024
    const int b    = in_sizes[0] / d;           // 2048
    const int m    = in_sizes[1] / d;           // 8192
    const int d2   = in_sizes[3];               // 2048
    const int outN = in_sizes[5];               // 1000
    const int outPad = 1024;

    unsigned short* xn    = (unsigned short*)d_ws;                    // [b][d] bf16
    unsigned short* yn    = xn  + (size_t)b * d;                      // [m][d] bf16
    float*          ynorm = (float*)(yn + (size_t)m * d);             // [m] fp32
    unsigned short* W1T   = (unsigned short*)(ynorm + m);             // [2d][d] bf16
    unsigned short* W2T   = W1T + (size_t)d2 * d;                     // [outPad][2d] bf16
    unsigned short* Zh    = W2T + (size_t)outPad * d2;                // [b][m] fp16
    unsigned short* mv    = Zh + (size_t)b * m;                       // [b][d] bf16
    unsigned short* h     = mv + (size_t)b * d;                       // [b][2d] bf16

    // normalize enc->xn and mem->yn (+norms) in one launch
    normalize_rows_bf16<<<b + m, TPB, 0, stream>>>(enc, xn, mem, yn, ynorm, b, d);

    // W1 [d][2d]->W1T [2d][d]  and  W2 [2d][outN]->W2T [outPad][2d] in one launch
    int nblk1 = (d2 / 32) * (d / 32);
    int nblk2 = (outPad / 32) * (d2 / 32);
    transpose_cast2<<<nblk1 + nblk2, TPB, 0, stream>>>(W1, W1T, d, d2, d2,
                                                       W2, W2T, d2, outN, outPad, nblk1);

    // Z = xn * yn^T  [b][m] fp16.  BM=256 x BN=128, 8 waves (512 thr).
    gemm_bt<256, 128, 64, 64, 2, 0, 0><<<dim3(m / 128, b / 256), 512, 0, stream>>>(
        xn, yn, nullptr, Zh, b, d, d, m, m);

    // fused sparsemax + bf16 gather -> mv
    sparsemax_gather<<<b, TPB, 0, stream>>>(Zh, ynorm, yn, mv, m, d);

    // h = relu(mv * W1 + b1)  [b][2d] bf16.  4 waves (256 thr).
    gemm_bt<128, 128, 64, 64, 1, 1, 1><<<dim3(d2 / 128, b / 128), 256, 0, stream>>>(
        mv, W1T, b1, h, b, d, d, d2, d2);

    // out = h * W2 + b2  [b][outN] fp32.  32x64 wave tiles -> 4 waves (256 thr).
    gemm_bt<128, 64, 32, 64, 0, 0, 1><<<dim3(outPad / 64, b / 128), 256, 0, stream>>>(
        h, W2T, b2, d_out, b, d2, d2, outN, outN);
}

// Round 10
// 245.856 us; speedup vs baseline: 1.2586x; 1.0705x over previous
//
#include <hip/hip_runtime.h>
#include <hip/hip_bf16.h>

// b=2048, m=8192, d=1024, 2d=2048, out=1000. fp32 in/out, bf16 MFMA GEMMs.
// Z (cosine scores) in fp16. sparsemax+gather fused; gather reads bf16 rows
// (fp8 gather tried r8: absmax 1.46e-2 > 1.18e-2 threshold — reverted).
// r11: Z row in registers (LDS 23->6.5KB), 60.5us. r12/r13: 512-thr
// REGRESSED. r14/r15: pipeline ARRAY -> scratch spill. r16: predicated
// weights cost VALU+occ. r17: fdot2 A + packed single-threshold B + fma_mix
// gather: 58us. r18: x8 unroll SPILLED (>64 VGPR window). r19: x6 unroll
// clean, 56.3us — +3% only => gather at L2/L3 random-row service asymptote.
// Sparsemax now 56/263us (21%). FROZEN at r19 form.
// r20: attack the OTHER 207us. GEMM2/GEMM3 each launch 256 blocks = 1
// block/CU: the 2-barrier K-loop's vmcnt(0)+barrier drain has no other
// resident block to hide it (m114 model) -> est ~200 TF, ~40us each.
// Reshape to grid=512 = 2 blocks/CU: GEMM2 64x128 tile (WM32/WN64),
// GEMM3 64x64 (WM32/WN32). Smaller tiles trade per-block eff for 2
// independent barrier streams/CU.
// GEMM: BMxBN block, WMxWN wave tiles, BK=64, XOR-swizzled LDS staging
// (0 bank conflicts, measured r5), shfl-packed epilogue stores.

#define TPB 256
#define CAP 1024   // compact-list capacity; fallback path if exceeded

typedef __bf16 bf16x8 __attribute__((ext_vector_type(8)));
typedef float  f32x4  __attribute__((ext_vector_type(4)));
typedef _Float16 half2_t __attribute__((ext_vector_type(2)));

typedef const __attribute__((address_space(1))) void* gas_ptr;
typedef __attribute__((address_space(3))) void*       las_ptr;

#if defined(__has_builtin)
# if __has_builtin(__builtin_amdgcn_fdot2) && __has_builtin(__builtin_elementwise_max)
#  define HAVE_PK16 1
# endif
#endif
#ifndef HAVE_PK16
# define HAVE_PK16 0
#endif

__device__ __forceinline__ unsigned short f2bf(float f) {
    __hip_bfloat16 h = __float2bfloat16(f);
    union { __hip_bfloat16 h; unsigned short s; } u; u.h = h; return u.s;
}
__device__ __forceinline__ float bf2f(unsigned short s) {
    union { unsigned int b; float f; } u; u.b = (unsigned int)s << 16; return u.f;
}
__device__ __forceinline__ unsigned short f2h(float f) {
    union { _Float16 h; unsigned short s; } u; u.h = (_Float16)f; return u.s;
}
__device__ __forceinline__ float h2f(unsigned short s) {
    union { unsigned short s; _Float16 h; } u; u.s = s; return (float)u.h;
}

__device__ __forceinline__ float block_reduce_sum(float v, float* sred) {
    #pragma unroll
    for (int off = 32; off > 0; off >>= 1) v += __shfl_down(v, off, 64);
    int lane = threadIdx.x & 63, wid = threadIdx.x >> 6;
    if (lane == 0) sred[wid] = v;
    __syncthreads();
    if (threadIdx.x == 0) sred[0] = sred[0] + sred[1] + sred[2] + sred[3];
    __syncthreads();
    float r = sred[0];
    __syncthreads();
    return r;
}

__device__ __forceinline__ void block_reduce_sum2(float& a, float& b, float* sred) {
    #pragma unroll
    for (int off = 32; off > 0; off >>= 1) {
        a += __shfl_down(a, off, 64);
        b += __shfl_down(b, off, 64);
    }
    int lane = threadIdx.x & 63, wid = threadIdx.x >> 6;
    if (lane == 0) { sred[wid] = a; sred[4 + wid] = b; }
    __syncthreads();
    if (threadIdx.x == 0) {
        sred[0] = sred[0] + sred[1] + sred[2] + sred[3];
        sred[4] = sred[4] + sred[5] + sred[6] + sred[7];
    }
    __syncthreads();
    a = sred[0]; b = sred[4];
    __syncthreads();
}

// Merged: rows [0,nrow0) normalize X0->Y0 (bf16); rest X1->Y1 (bf16) + norm.
__global__ __launch_bounds__(TPB) void normalize_rows_bf16(const float* __restrict__ X0,
                                                           unsigned short* __restrict__ Y0,
                                                           const float* __restrict__ X1,
                                                           unsigned short* __restrict__ Y1,
                                                           float* __restrict__ norms1,
                                                           int nrow0, int cols) {
    __shared__ float sred[4];
    int r = blockIdx.x, tid = threadIdx.x;
    const float* X; unsigned short* Y; float* nn; int row;
    if (r < nrow0) { X = X0; Y = Y0; nn = nullptr; row = r; }
    else           { X = X1; Y = Y1; nn = norms1; row = r - nrow0; }
    const float4* x4 = (const float4*)(X + (size_t)row * cols);
    ushort4* y4 = (ushort4*)(Y + (size_t)row * cols);
    int n4 = cols >> 2;
    float ss = 0.f;
    for (int i = tid; i < n4; i += TPB) {
        float4 v = x4[i];
        ss += v.x * v.x + v.y * v.y + v.z * v.z + v.w * v.w;
    }
    float tot = block_reduce_sum(ss, sred);
    float nrm = sqrtf(tot + 1e-6f);
    float inv = 1.0f / nrm;
    if (nn && tid == 0) nn[row] = nrm;
    for (int i = tid; i < n4; i += TPB) {
        float4 v = x4[i];
        ushort4 o;
        o.x = f2bf(v.x * inv); o.y = f2bf(v.y * inv);
        o.z = f2bf(v.z * inv); o.w = f2bf(v.w * inv);
        y4[i] = o;
    }
}

// Two transposes (W1 and W2) in one launch. in fp32 [R][C] -> out bf16 [Cpad][R].
__device__ __forceinline__ void tc_body(const float* in, unsigned short* out,
                                        int R, int C, int Cpad, int bx, int by) {
    __shared__ float t[32][33];
    int x = threadIdx.x & 31, y = threadIdx.x >> 5;
    int r0 = by * 32, c0 = bx * 32;
    #pragma unroll
    for (int yy = y; yy < 32; yy += 8) {
        int c = c0 + x;
        t[yy][x] = (c < C) ? in[(size_t)(r0 + yy) * C + c] : 0.f;
    }
    __syncthreads();
    #pragma unroll
    for (int yy = y; yy < 32; yy += 8) {
        int c = c0 + yy;
        if (c < Cpad)
            out[(size_t)c * R + r0 + x] = f2bf(t[x][yy]);
    }
}

__global__ __launch_bounds__(TPB) void transpose_cast2(const float* __restrict__ in1,
                                                       unsigned short* __restrict__ out1,
                                                       int R1, int C1, int Cp1,
                                                       const float* __restrict__ in2,
                                                       unsigned short* __restrict__ out2,
                                                       int R2, int C2, int Cp2,
                                                       int nblk1) {
    int bid = blockIdx.x;
    if (bid < nblk1) {
        int nx = Cp1 / 32;
        tc_body(in1, out1, R1, C1, Cp1, bid % nx, bid / nx);
    } else {
        bid -= nblk1;
        int nx = Cp2 / 32;
        tc_body(in2, out2, R2, C2, Cp2, bid % nx, bid / nx);
    }
}

// acc += w * row (bf16x8). (float)__bf16 + fmaf lets gfx950 pattern-match
// v_fma_mix_f32_bf16 (no explicit unpack); falls back to shift+fma harmlessly.
__device__ __forceinline__ void acc8b(float* acc, float w, bf16x8 v) {
    #pragma unroll
    for (int k = 0; k < 8; ++k)
        acc[k] = fmaf(w, (float)v[k], acc[k]);
}

// Fused sparsemax (Michelot, exact, moment head-start) + bf16 gather:
// mv[row] = sum_i sparsemax(z)_i * mem_i = sum_i (z_i - tau) * ynorm_i * yhat_i.
// Z row in registers for Pass A-C only: NR=4 uint4/thread (m = TPB*8*NR).
__global__ __launch_bounds__(TPB, 8) void sparsemax_gather(const unsigned short* __restrict__ Zh,
                                                           const float* __restrict__ ynorm,
                                                           const unsigned short* __restrict__ yn,
                                                           unsigned short* __restrict__ mv,
                                                           int m, int d) {
    __shared__ float sred[16];
    __shared__ unsigned short cidx[CAP];
    __shared__ float cval[CAP];        // z during Michelot; weights after fold;
                                       // transposed combine scratch at the end
    __shared__ unsigned int lcnt;
    constexpr int NR = 4;              // m / (TPB*8)
    int row = blockIdx.x, tid = threadIdx.x;
    const uint4* zr8 = (const uint4*)(Zh + (size_t)row * m);

    float tau1;
    {
        // zreg scope ends at Pass C so its 16 VGPRs are reusable by the
        // gather (fallback re-reads global Z; r14 spill lesson).
        uint4 zreg[NR];
        float s = 0.f, q = 0.f;
#if HAVE_PK16
        const half2_t ones2 = {(_Float16)1.f, (_Float16)1.f};
#endif
        // Pass A: load row + sum + sumsq (fdot2: 1 op/elem).
        #pragma unroll
        for (int j = 0; j < NR; ++j) {
            uint4 v = zr8[tid + j * TPB];
            zreg[j] = v;
            unsigned int ww[4] = {v.x, v.y, v.z, v.w};
            #pragma unroll
            for (int k = 0; k < 4; ++k) {
#if HAVE_PK16
                union { unsigned int u; half2_t h; } pu; pu.u = ww[k];
                s = __builtin_amdgcn_fdot2(pu.h, ones2, s, false);
                q = __builtin_amdgcn_fdot2(pu.h, pu.h, q, false);
#else
                float a = h2f((unsigned short)(ww[k] & 0xffffu));
                float bq = h2f((unsigned short)(ww[k] >> 16));
                s += a + bq; q += a * a + bq * bq;
#endif
            }
        }
        if (tid == 0) lcnt = 0;
        block_reduce_sum2(s, q, sred);
        float fm   = (float)m;
        float mean = s / fm;
        float sig  = sqrtf(fmaxf(q / fm - mean * mean, 0.f));
        float tau_s = (s - 1.f) / fm;
        // quantize tau_g to f16 so packed stats are exactly "stats at tgf"
        _Float16 tgh = (_Float16)(mean + 2.f * sig);
        float tgf = (float)tgh;

        // Pass B: excess-sum & count at tau_g ONLY (common case).
        float Sg = 0.f, cg = 0.f;
#if HAVE_PK16
        const half2_t tg2 = {tgh, tgh};
        const half2_t zero2 = {(_Float16)0.f, (_Float16)0.f};
#endif
        #pragma unroll
        for (int j = 0; j < NR; ++j) {
            unsigned int ww[4] = {zreg[j].x, zreg[j].y, zreg[j].z, zreg[j].w};
            #pragma unroll
            for (int k = 0; k < 4; ++k) {
#if HAVE_PK16
                union { unsigned int u; half2_t h; } pu; pu.u = ww[k];
                half2_t e = __builtin_elementwise_max(pu.h - tg2, zero2);
                Sg = __builtin_amdgcn_fdot2(e, ones2, Sg, false);
                if (e[0] > (_Float16)0.f) cg += 1.f;
                if (e[1] > (_Float16)0.f) cg += 1.f;
#else
                float a = h2f((unsigned short)(ww[k] & 0xffffu));
                float bq = h2f((unsigned short)(ww[k] >> 16));
                if (a > tgf)  { Sg += a - tgf;  cg += 1.f; }
                if (bq > tgf) { Sg += bq - tgf; cg += 1.f; }
#endif
            }
        }
        block_reduce_sum2(Sg, cg, sred);

        if (Sg >= 1.f) {
            tau1 = tgf + (Sg - 1.f) / cg;          // Michelot step from tgf
            if (tau1 < tgf) tau1 = tgf;
        } else {
            // rare: weak tail. Exact stats at the safe lower bound tau_s.
            float Ss = 0.f, cs = 0.f;
            #pragma unroll
            for (int j = 0; j < NR; ++j) {
                unsigned int ww[4] = {zreg[j].x, zreg[j].y, zreg[j].z, zreg[j].w};
                #pragma unroll
                for (int k = 0; k < 4; ++k) {
                    float a = h2f((unsigned short)(ww[k] & 0xffffu));
                    float bq = h2f((unsigned short)(ww[k] >> 16));
                    if (a > tau_s)  { Ss += a - tau_s;  cs += 1.f; }
                    if (bq > tau_s) { Ss += bq - tau_s; cs += 1.f; }
                }
            }
            block_reduce_sum2(Ss, cs, sred);
            tau1 = tau_s + (Ss - 1.f) / cs;
            if (tau1 < tau_s) tau1 = tau_s;
        }

        // Pass C: compact actives at tau1 (exact f32 compares).
        #pragma unroll
        for (int j = 0; j < NR; ++j) {
            int base = (tid + j * TPB) * 8;
            unsigned int ww[4] = {zreg[j].x, zreg[j].y, zreg[j].z, zreg[j].w};
            #pragma unroll
            for (int k = 0; k < 4; ++k) {
                float a = h2f((unsigned short)(ww[k] & 0xffffu));
                float bq = h2f((unsigned short)(ww[k] >> 16));
                if (a > tau1) {
                    unsigned int slot = atomicAdd(&lcnt, 1u);
                    if (slot < CAP) { cidx[slot] = (unsigned short)(base + 2 * k); cval[slot] = a; }
                }
                if (bq > tau1) {
                    unsigned int slot = atomicAdd(&lcnt, 1u);
                    if (slot < CAP) { cidx[slot] = (unsigned short)(base + 2 * k + 1); cval[slot] = bq; }
                }
            }
        }
    }
    __syncthreads();

    int fast = (lcnt <= CAP && lcnt > 0);
    float tau = tau1;
    int n = (int)lcnt;
    if (fast) {
        // list-Michelot on wave 0 only (n <= 1024): shuffle reductions, no
        // block-wide barriers inside the iteration loop.
        if ((tid >> 6) == 0) {
            int lane = tid & 63;
            float tau_l = tau1, prev = -1.f;
            for (int it = 0; it < 64; ++it) {
                float S = 0.f, c = 0.f;
                for (int jj = lane; jj < n; jj += 64) {
                    float z = cval[jj];
                    if (z > tau_l) { S += z; c += 1.f; }
                }
                #pragma unroll
                for (int off = 32; off > 0; off >>= 1) {
                    S += __shfl_down(S, off, 64);
                    c += __shfl_down(c, off, 64);
                }
                S = __shfl(S, 0, 64);
                c = __shfl(c, 0, 64);
                if (c < 0.5f || c == prev) break;
                tau_l = (S - 1.f) / c; prev = c;
            }
            if (lane == 0) sred[0] = tau_l;
        }
        __syncthreads();
        tau = sred[0];
        // fold norm into weights (<=0 entries become 0; gather is branchless)
        for (int jj = tid; jj < n; jj += TPB) {
            float w = cval[jj] - tau;
            cval[jj] = (w > 0.f) ? w * ynorm[cidx[jj]] : 0.f;
        }
        __syncthreads();
    } else {
        // rare: n > CAP. Michelot re-reading Z from global (L2/L3-resident).
        float prev = -1.f;
        for (int it = 0; it < 64; ++it) {
            float S = 0.f, c = 0.f;
            for (int i8 = tid; i8 < (m >> 3); i8 += TPB) {
                uint4 v = zr8[i8];
                unsigned int ww[4] = {v.x, v.y, v.z, v.w};
                #pragma unroll
                for (int k = 0; k < 4; ++k) {
                    float a = h2f((unsigned short)(ww[k] & 0xffffu));
                    float bq = h2f((unsigned short)(ww[k] >> 16));
                    if (a > tau) { S += a; c += 1.f; }
                    if (bq > tau) { S += bq; c += 1.f; }
                }
            }
            block_reduce_sum2(S, c, sred);
            if (c < 0.5f || c == prev) break;
            tau = (S - 1.f) / c; prev = c;
        }
    }

    // Gather (bf16 rows, 2 KB each): two 128-thread groups, 8 cols/thread.
    // x6 unroll, TRANSIENT named scalars (6 loads in flight; x8 spilled r18).
    int g = tid >> 7;
    int c0 = (tid & 127) * 8;    // d = 1024 = 128*8
    float acc[8] = {};
    if (fast) {
        int j = g;
        for (; j + 10 < n; j += 12) {
            int i0 = cidx[j],      i1 = cidx[j + 2];
            int i2 = cidx[j + 4],  i3 = cidx[j + 6];
            int i4 = cidx[j + 8],  i5 = cidx[j + 10];
            float w0 = cval[j],      w1 = cval[j + 2];
            float w2 = cval[j + 4],  w3 = cval[j + 6];
            float w4 = cval[j + 8],  w5 = cval[j + 10];
            bf16x8 v0 = *(const bf16x8*)&yn[(size_t)i0 * d + c0];
            bf16x8 v1 = *(const bf16x8*)&yn[(size_t)i1 * d + c0];
            bf16x8 v2 = *(const bf16x8*)&yn[(size_t)i2 * d + c0];
            bf16x8 v3 = *(const bf16x8*)&yn[(size_t)i3 * d + c0];
            bf16x8 v4 = *(const bf16x8*)&yn[(size_t)i4 * d + c0];
            bf16x8 v5 = *(const bf16x8*)&yn[(size_t)i5 * d + c0];
            acc8b(acc, w0, v0); acc8b(acc, w1, v1);
            acc8b(acc, w2, v2); acc8b(acc, w3, v3);
            acc8b(acc, w4, v4); acc8b(acc, w5, v5);
        }
        for (; j < n; j += 2) {
            float w = cval[j];
            int idx = (int)cidx[j];
            bf16x8 v = *(const bf16x8*)&yn[(size_t)idx * d + c0];
            acc8b(acc, w, v);
        }
    } else {
        // rare path: weights recomputed from global Z (L2/L3-resident)
        const unsigned short* zrow = Zh + (size_t)row * m;
        for (int i = g; i < m; i += 2) {
            float w = h2f(zrow[i]) - tau;
            if (w <= 0.f) continue;
            w *= ynorm[i];
            bf16x8 v = *(const bf16x8*)&yn[(size_t)i * d + c0];
            acc8b(acc, w, v);
        }
    }
    __syncthreads();
    // combine: transposed layout (lanes write consecutive 4B -> no conflicts)
    int tcol = tid & 127;
    if (g == 1) {
        #pragma unroll
        for (int k = 0; k < 8; ++k) cval[k * 128 + tcol] = acc[k];
    }
    __syncthreads();
    if (g == 0) {
        #pragma unroll
        for (int k = 0; k < 8; ++k) acc[k] += cval[k * 128 + tcol];
        unsigned int w0 = f2bf(acc[0]) | ((unsigned int)f2bf(acc[1]) << 16);
        unsigned int w1 = f2bf(acc[2]) | ((unsigned int)f2bf(acc[3]) << 16);
        unsigned int w2 = f2bf(acc[4]) | ((unsigned int)f2bf(acc[5]) << 16);
        unsigned int w3 = f2bf(acc[6]) | ((unsigned int)f2bf(acc[7]) << 16);
        uint4 st = {w0, w1, w2, w3};
        *(uint4*)&mv[(size_t)row * d + c0] = st;
    }
}

// C[M][ldc] = A[M][lda] * B^T (+bias)(+relu). B is [Npad][K] bf16 row-major.
// BM x BN block tile, WM x WN wave tiles, BK=64, XOR-swizzled staging
// (swizzle on global addr; LDS dest lane-contiguous). Launch (BM/WM)*(BN/WN)*64 thr.
// OUTMODE: 0=f32, 1=bf16, 2=f16.
template <int BM, int BN, int WM, int WN, int OUTMODE, int RELU, int HASBIAS>
__global__ __launch_bounds__((BM / WM) * (BN / WN) * 64)
void gemm_bt(const unsigned short* __restrict__ A,
             const unsigned short* __restrict__ B,
             const float* __restrict__ bias,
             void* __restrict__ C,
             int M, int K, int lda, int NOUT, int ldc) {
    constexpr int NW   = (BM / WM) * (BN / WN);
    constexpr int TPBL = NW * 64;
    constexpr int ITM  = WM / 16;
    constexpr int ITN  = WN / 16;
    __shared__ unsigned short lA[BM * 64];
    __shared__ unsigned short lB[BN * 64];
    int tid = threadIdx.x;
    int lane = tid & 63, wv = tid >> 6;
    int wm = (wv % (BM / WM)) * WM;
    int wn = (wv / (BM / WM)) * WN;
    int lr = lane & 15, kq = lane >> 4;

    int rowBase = blockIdx.y * BM;
    int colBase = blockIdx.x * BN;

    f32x4 acc[ITM][ITN] = {};

    for (int k0 = 0; k0 < K; k0 += 64) {
        constexpr int AI = BM * 8 / TPBL;
        #pragma unroll
        for (int l = 0; l < AI; ++l) {
            int li = l * TPBL + tid;
            int row = li >> 3, s0 = li & 7;
            int seg = s0 ^ (row & 7);
            const char* gp = (const char*)(A + (size_t)(rowBase + row) * lda + k0) + seg * 16;
            __builtin_amdgcn_global_load_lds((gas_ptr)gp, (las_ptr)((char*)lA + li * 16), 16, 0, 0);
        }
        constexpr int BI = BN * 8 / TPBL;
        #pragma unroll
        for (int l = 0; l < BI; ++l) {
            int li = l * TPBL + tid;
            int row = li >> 3, s0 = li & 7;
            int seg = s0 ^ (row & 7);
            const char* gp = (const char*)(B + (size_t)(colBase + row) * K + k0) + seg * 16;
            __builtin_amdgcn_global_load_lds((gas_ptr)gp, (las_ptr)((char*)lB + li * 16), 16, 0, 0);
        }
        __syncthreads();

        #pragma unroll
        for (int h = 0; h < 2; ++h) {
            bf16x8 av[ITM], bv[ITN];
            #pragma unroll
            for (int i = 0; i < ITM; ++i) {
                int row = wm + i * 16 + lr;
                av[i] = *(const bf16x8*)((const char*)lA + row * 128
                                         + ((((h << 2) | kq) ^ (row & 7)) * 16));
            }
            #pragma unroll
            for (int j = 0; j < ITN; ++j) {
                int row = wn + j * 16 + lr;
                bv[j] = *(const bf16x8*)((const char*)lB + row * 128
                                         + ((((h << 2) | kq) ^ (row & 7)) * 16));
            }
            #pragma unroll
            for (int i = 0; i < ITM; ++i)
                #pragma unroll
                for (int j = 0; j < ITN; ++j)
                    acc[i][j] = __builtin_amdgcn_mfma_f32_16x16x32_bf16(av[i], bv[j], acc[i][j], 0, 0, 0);
        }
        __syncthreads();
    }

    // Epilogue. C/D layout: col = lane&15, row = kq*4+r. Packed stores.
    float* Cf = (float*)C;
    unsigned short* Cb = (unsigned short*)C;
    bool fullN = (colBase + BN) <= NOUT;
    #pragma unroll
    for (int j = 0; j < ITN; ++j) {
        int col = colBase + wn + j * 16 + lr;
        float bv_ = (HASBIAS && col < NOUT) ? bias[col] : 0.f;
        #pragma unroll
        for (int i = 0; i < ITM; ++i) {
            #pragma unroll
            for (int r = 0; r < 4; ++r) {
                int row = rowBase + wm + i * 16 + kq * 4 + r;
                float v = acc[i][j][r] + bv_;
                if (RELU) v = fmaxf(v, 0.f);
                if (OUTMODE == 0) {
                    float p = __shfl_xor(v, 1, 64);
                    if (fullN) {
                        if (!(lr & 1)) { float2 st = {v, p}; *(float2*)&Cf[(size_t)row * ldc + col] = st; }
                    } else if (col < NOUT) {
                        Cf[(size_t)row * ldc + col] = v;
                    }
                } else {
                    unsigned int hh = (OUTMODE == 1) ? (unsigned int)f2bf(v) : (unsigned int)f2h(v);
                    unsigned int p1 = (unsigned int)__shfl_xor((int)hh, 1, 64);
                    unsigned int u = (hh & 0xffffu) | (p1 << 16);
                    unsigned int p2 = (unsigned int)__shfl_xor((int)u, 2, 64);
                    if (fullN) {
                        if (!(lr & 3)) { uint2 st = {u, p2}; *(uint2*)&Cb[(size_t)row * ldc + col] = st; }
                    } else if (col < NOUT) {
                        Cb[(size_t)row * ldc + col] = (unsigned short)hh;
                    }
                }
            }
        }
    }
}

extern "C" void kernel_launch(void* const* d_in, const int* in_sizes, int n_in,
                              void* d_out, int out_size, void* d_ws, size_t ws_size,
                              hipStream_t stream) {
    const float* enc = (const float*)d_in[0];   // [b, d]
    const float* mem = (const float*)d_in[1];   // [m, d]
    const float* W1  = (const float*)d_in[2];   // [d, 2d]
    const float* b1  = (const float*)d_in[3];   // [2d]
    const float* W2  = (const float*)d_in[4];   // [2d, out]
    const float* b2  = (const float*)d_in[5];   // [out]

    const int d    = in_sizes[3] / 2;           // 1024
    const int b    = in_sizes[0] / d;           // 2048
    const int m    = in_sizes[1] / d;           // 8192
    const int d2   = in_sizes[3];               // 2048
    const int outN = in_sizes[5];               // 1000
    const int outPad = 1024;

    unsigned short* xn    = (unsigned short*)d_ws;                    // [b][d] bf16
    unsigned short* yn    = xn  + (size_t)b * d;                      // [m][d] bf16
    float*          ynorm = (float*)(yn + (size_t)m * d);             // [m] fp32
    unsigned short* W1T   = (unsigned short*)(ynorm + m);             // [2d][d] bf16
    unsigned short* W2T   = W1T + (size_t)d2 * d;                     // [outPad][2d] bf16
    unsigned short* Zh    = W2T + (size_t)outPad * d2;                // [b][m] fp16
    unsigned short* mv    = Zh + (size_t)b * m;                       // [b][d] bf16
    unsigned short* h     = mv + (size_t)b * d;                       // [b][2d] bf16

    // normalize enc->xn and mem->yn (+norms) in one launch
    normalize_rows_bf16<<<b + m, TPB, 0, stream>>>(enc, xn, mem, yn, ynorm, b, d);

    // W1 [d][2d]->W1T [2d][d]  and  W2 [2d][outN]->W2T [outPad][2d] in one launch
    int nblk1 = (d2 / 32) * (d / 32);
    int nblk2 = (outPad / 32) * (d2 / 32);
    transpose_cast2<<<nblk1 + nblk2, TPB, 0, stream>>>(W1, W1T, d, d2, d2,
                                                       W2, W2T, d2, outN, outPad, nblk1);

    // Z = xn * yn^T  [b][m] fp16.  BM=256 x BN=128, 8 waves (512 thr).
    gemm_bt<256, 128, 64, 64, 2, 0, 0><<<dim3(m / 128, b / 256), 512, 0, stream>>>(
        xn, yn, nullptr, Zh, b, d, d, m, m);

    // fused sparsemax + bf16 gather -> mv
    sparsemax_gather<<<b, TPB, 0, stream>>>(Zh, ynorm, yn, mv, m, d);

    // h = relu(mv * W1 + b1)  [b][2d] bf16.  64x128 tile, 4 waves,
    // grid 16x32 = 512 blocks = 2/CU (r20: was 128x128 @ 256 blocks = 1/CU).
    gemm_bt<64, 128, 32, 64, 1, 1, 1><<<dim3(d2 / 128, b / 64), 256, 0, stream>>>(
        mv, W1T, b1, h, b, d, d, d2, d2);

    // out = h * W2 + b2  [b][outN] fp32.  64x64 tile, 4 waves,
    // grid 16x32 = 512 blocks = 2/CU (r20: was 128x64 @ 256 blocks = 1/CU).
    gemm_bt<64, 64, 32, 32, 0, 0, 1><<<dim3(outPad / 64, b / 64), 256, 0, stream>>>(
        h, W2T, b2, d_out, b, d2, d2, outN, outN);
}